// Round 3
// baseline (218.778 us; speedup 1.0000x reference)
//
#include <hip/hip_runtime.h>

// FilteredLReLU: up2(17-tap) -> *2 -> lrelu(0.01) -> down2(17-tap), fused.
// Two-stage shared-intermediate version:
//   stage A: each thread computes (ge,go) pairs straight from global x,
//            writes them to LDS (full sharing -> no redundant up-conv FMAs)
//   stage B: each thread computes 8 outputs from LDS ge/go windows.
//
//   ge[m] = lrelu( sum_{j=0..8} fe[j]*x[m-4+j] )   if 0<=m<T else 0
//   go[m] = lrelu( sum_{j=0..7} fo[j]*x[m-3+j] )   if 0<=m<T else 0
//   z[t]  = sum_{j=0..8} de[j]*ge[t-4+j] + sum_{j=0..7} dd[j]*go[t-4+j]
// (UP gain of 2 folded into fe/fo.)

#define T_LEN  32768
#define TILE   2048
#define NTILES (T_LEN / TILE)     // 16
#define HALO   4
#define NI     (TILE + 2 * HALO)  // 2056 intermediate pairs per block
#define NG     (NI / 4)           // 514 groups of 4 pairs

__device__ __forceinline__ float lrelu(float v) {
    return v >= 0.0f ? v : 0.01f * v;
}

__global__ __launch_bounds__(256) void flrelu_2stage(
    const float* __restrict__ x,
    const float* __restrict__ up,
    const float* __restrict__ dn,
    float* __restrict__ out)
{
    __shared__ __align__(16) float sge[NI + 8];
    __shared__ __align__(16) float sgo[NI + 8];

    const int tid  = threadIdx.x;
    const int row  = blockIdx.x >> 4;            // / NTILES
    const int tile = blockIdx.x & (NTILES - 1);
    const int t0   = tile * TILE;
    const float* __restrict__ xrow = x + (size_t)row * T_LEN;
    float* __restrict__ orow       = out + (size_t)row * T_LEN;

    // Filters (uniform -> scalar loads). UP gain folded into fe/fo.
    float fe[9], fo[8], de[9], dd[8];
    #pragma unroll
    for (int j = 0; j < 9; ++j) { fe[j] = 2.0f * up[2 * j]; de[j] = dn[2 * j]; }
    #pragma unroll
    for (int j = 0; j < 8; ++j) { fo[j] = 2.0f * up[2 * j + 1]; dd[j] = dn[2 * j + 1]; }

    // ---- stage A: x (global) -> ge/go (LDS) ----
    const bool interior = (tile > 0) && (tile < NTILES - 1);
    if (interior) {
        for (int g = tid; g < NG; g += 256) {
            const int li = 4 * g;                 // lds index of first pair
            const int m0 = t0 - HALO + li;        // first intermediate pos
            // x[m0-4 .. m0+7]: 12 floats, (m0-4) % 4 == 0 -> 3 aligned float4
            const float4* xp = reinterpret_cast<const float4*>(xrow + m0 - 4);
            float4 a = xp[0], b = xp[1], c = xp[2];
            float xv[12] = {a.x, a.y, a.z, a.w, b.x, b.y, b.z, b.w,
                            c.x, c.y, c.z, c.w};
            float ge_[4], go_[4];
            #pragma unroll
            for (int r = 0; r < 4; ++r) {
                float ae = 0.0f, ao = 0.0f;
                #pragma unroll
                for (int j = 0; j < 9; ++j) ae = fmaf(fe[j], xv[r + j], ae);
                #pragma unroll
                for (int j = 0; j < 8; ++j) ao = fmaf(fo[j], xv[r + 1 + j], ao);
                ge_[r] = lrelu(ae);
                go_[r] = lrelu(ao);
            }
            *reinterpret_cast<float4*>(&sge[li]) =
                make_float4(ge_[0], ge_[1], ge_[2], ge_[3]);
            *reinterpret_cast<float4*>(&sgo[li]) =
                make_float4(go_[0], go_[1], go_[2], go_[3]);
        }
    } else {
        for (int g = tid; g < NG; g += 256) {
            const int li = 4 * g;
            const int m0 = t0 - HALO + li;
            float xv[12];
            #pragma unroll
            for (int i = 0; i < 12; ++i) {
                int gx = m0 - 4 + i;
                xv[i] = (gx >= 0 && gx < T_LEN) ? xrow[gx] : 0.0f;
            }
            float ge_[4], go_[4];
            #pragma unroll
            for (int r = 0; r < 4; ++r) {
                float ae = 0.0f, ao = 0.0f;
                #pragma unroll
                for (int j = 0; j < 9; ++j) ae = fmaf(fe[j], xv[r + j], ae);
                #pragma unroll
                for (int j = 0; j < 8; ++j) ao = fmaf(fo[j], xv[r + 1 + j], ao);
                int m = m0 + r;
                bool valid = (m >= 0) && (m < T_LEN);   // dn conv zero-pads y
                ge_[r] = valid ? lrelu(ae) : 0.0f;
                go_[r] = valid ? lrelu(ao) : 0.0f;
            }
            *reinterpret_cast<float4*>(&sge[li]) =
                make_float4(ge_[0], ge_[1], ge_[2], ge_[3]);
            *reinterpret_cast<float4*>(&sgo[li]) =
                make_float4(go_[0], go_[1], go_[2], go_[3]);
        }
    }
    __syncthreads();

    // ---- stage B: ge/go (LDS) -> out (global), 8 outputs per thread ----
    {
        const int base = 8 * tid;                 // = (t - t0), t = t0 + base
        float e[16], o[16];
        #pragma unroll
        for (int k = 0; k < 4; ++k) {
            float4 v = *reinterpret_cast<const float4*>(&sge[base + 4 * k]);
            e[4 * k + 0] = v.x; e[4 * k + 1] = v.y;
            e[4 * k + 2] = v.z; e[4 * k + 3] = v.w;
            float4 w = *reinterpret_cast<const float4*>(&sgo[base + 4 * k]);
            o[4 * k + 0] = w.x; o[4 * k + 1] = w.y;
            o[4 * k + 2] = w.z; o[4 * k + 3] = w.w;
        }
        float z[8];
        #pragma unroll
        for (int r = 0; r < 8; ++r) {
            float acc = 0.0f;
            #pragma unroll
            for (int j = 0; j < 9; ++j) acc = fmaf(de[j], e[r + j], acc);
            #pragma unroll
            for (int j = 0; j < 8; ++j) acc = fmaf(dd[j], o[r + j], acc);
            z[r] = acc;
        }
        float4* op = reinterpret_cast<float4*>(&orow[t0 + base]);
        op[0] = make_float4(z[0], z[1], z[2], z[3]);
        op[1] = make_float4(z[4], z[5], z[6], z[7]);
    }
}

extern "C" void kernel_launch(void* const* d_in, const int* in_sizes, int n_in,
                              void* d_out, int out_size, void* d_ws, size_t ws_size,
                              hipStream_t stream) {
    const float* x  = (const float*)d_in[0];
    const float* up = (const float*)d_in[1];
    const float* dn = (const float*)d_in[2];
    float* out      = (float*)d_out;

    const int rows = in_sizes[0] / T_LEN;        // 2048
    dim3 grid(rows * NTILES);                    // 32768 blocks
    flrelu_2stage<<<grid, 256, 0, stream>>>(x, up, dn, out);
}

// Round 4
// 204.091 us; speedup vs baseline: 1.0720x; 1.0720x over previous
//
#include <hip/hip_runtime.h>

// FilteredLReLU: up2(17-tap) -> *2 -> lrelu(0.01) -> down2(17-tap), fused.
// Two-stage shared-intermediate version with PADDED LDS layout:
//   one float4 of pad inserted every 8 float4 groups
//   (phys = li + 4*(li>>5)) so both the 16B-stride writes and the
//   32B-stride windowed reads distribute uniformly over the 8
//   4-bank clusters -> baseline (conflict-free) b128 throughput.
//
//   ge[m] = lrelu( sum_{j=0..8} fe[j]*x[m-4+j] )   if 0<=m<T else 0
//   go[m] = lrelu( sum_{j=0..7} fo[j]*x[m-3+j] )   if 0<=m<T else 0
//   z[t]  = sum_{j=0..8} de[j]*ge[t-4+j] + sum_{j=0..7} dd[j]*go[t-4+j]
// (UP gain of 2 folded into fe/fo.)

#define T_LEN  32768
#define TILE   2048
#define NTILES (T_LEN / TILE)     // 16
#define HALO   4
#define NI     (TILE + 2 * HALO)  // 2056 intermediates per block
#define NG     (NI / 4)           // 514 float4 groups
#define PAD_N  (NI + 4 * (NI / 32) + 8)   // padded float count per array

__device__ __forceinline__ float lrelu(float v) {
    return v >= 0.0f ? v : 0.01f * v;
}

// float index -> padded float index (li must be a multiple of 4)
__device__ __forceinline__ int padi(int li) {
    return li + ((li >> 5) << 2);
}

__global__ __launch_bounds__(256) void flrelu_pad(
    const float* __restrict__ x,
    const float* __restrict__ up,
    const float* __restrict__ dn,
    float* __restrict__ out)
{
    __shared__ __align__(16) float sge[PAD_N];
    __shared__ __align__(16) float sgo[PAD_N];

    const int tid  = threadIdx.x;
    const int row  = blockIdx.x >> 4;            // / NTILES
    const int tile = blockIdx.x & (NTILES - 1);
    const int t0   = tile * TILE;
    const float* __restrict__ xrow = x + (size_t)row * T_LEN;
    float* __restrict__ orow       = out + (size_t)row * T_LEN;

    // Filters (uniform -> scalar loads). UP gain folded into fe/fo.
    float fe[9], fo[8], de[9], dd[8];
    #pragma unroll
    for (int j = 0; j < 9; ++j) { fe[j] = 2.0f * up[2 * j]; de[j] = dn[2 * j]; }
    #pragma unroll
    for (int j = 0; j < 8; ++j) { fo[j] = 2.0f * up[2 * j + 1]; dd[j] = dn[2 * j + 1]; }

    // ---- stage A: x (global) -> ge/go (LDS, padded layout) ----
    const bool interior = (tile > 0) && (tile < NTILES - 1);
    if (interior) {
        #pragma unroll
        for (int it = 0; it < 3; ++it) {
            int g = tid + it * 256;
            if (it == 2 && g >= NG) break;        // NG = 514: only 2 threads iter 3
            const int li = 4 * g;
            const int m0 = t0 - HALO + li;
            const float4* xp = reinterpret_cast<const float4*>(xrow + m0 - 4);
            float4 a = xp[0], b = xp[1], c = xp[2];
            float xv[12] = {a.x, a.y, a.z, a.w, b.x, b.y, b.z, b.w,
                            c.x, c.y, c.z, c.w};
            float ge_[4], go_[4];
            #pragma unroll
            for (int r = 0; r < 4; ++r) {
                float ae = 0.0f, ao = 0.0f;
                #pragma unroll
                for (int j = 0; j < 9; ++j) ae = fmaf(fe[j], xv[r + j], ae);
                #pragma unroll
                for (int j = 0; j < 8; ++j) ao = fmaf(fo[j], xv[r + 1 + j], ao);
                ge_[r] = lrelu(ae);
                go_[r] = lrelu(ao);
            }
            const int pi = padi(li);
            *reinterpret_cast<float4*>(&sge[pi]) =
                make_float4(ge_[0], ge_[1], ge_[2], ge_[3]);
            *reinterpret_cast<float4*>(&sgo[pi]) =
                make_float4(go_[0], go_[1], go_[2], go_[3]);
        }
    } else {
        #pragma unroll
        for (int it = 0; it < 3; ++it) {
            int g = tid + it * 256;
            if (g >= NG) break;
            const int li = 4 * g;
            const int m0 = t0 - HALO + li;
            float xv[12];
            #pragma unroll
            for (int i = 0; i < 12; ++i) {
                int gx = m0 - 4 + i;
                xv[i] = (gx >= 0 && gx < T_LEN) ? xrow[gx] : 0.0f;
            }
            float ge_[4], go_[4];
            #pragma unroll
            for (int r = 0; r < 4; ++r) {
                float ae = 0.0f, ao = 0.0f;
                #pragma unroll
                for (int j = 0; j < 9; ++j) ae = fmaf(fe[j], xv[r + j], ae);
                #pragma unroll
                for (int j = 0; j < 8; ++j) ao = fmaf(fo[j], xv[r + 1 + j], ao);
                int m = m0 + r;
                bool valid = (m >= 0) && (m < T_LEN);   // dn conv zero-pads y
                ge_[r] = valid ? lrelu(ae) : 0.0f;
                go_[r] = valid ? lrelu(ao) : 0.0f;
            }
            const int pi = padi(li);
            *reinterpret_cast<float4*>(&sge[pi]) =
                make_float4(ge_[0], ge_[1], ge_[2], ge_[3]);
            *reinterpret_cast<float4*>(&sgo[pi]) =
                make_float4(go_[0], go_[1], go_[2], go_[3]);
        }
    }
    __syncthreads();

    // ---- stage B: ge/go (LDS) -> out (global), 8 outputs per thread ----
    {
        const int base = 8 * tid;                 // output t = t0 + base
        float e[16], o[16];
        #pragma unroll
        for (int k = 0; k < 4; ++k) {
            const int pi = padi(base + 4 * k);
            float4 v = *reinterpret_cast<const float4*>(&sge[pi]);
            e[4 * k + 0] = v.x; e[4 * k + 1] = v.y;
            e[4 * k + 2] = v.z; e[4 * k + 3] = v.w;
            float4 w = *reinterpret_cast<const float4*>(&sgo[pi]);
            o[4 * k + 0] = w.x; o[4 * k + 1] = w.y;
            o[4 * k + 2] = w.z; o[4 * k + 3] = w.w;
        }
        float z[8];
        #pragma unroll
        for (int r = 0; r < 8; ++r) {
            float acc = 0.0f;
            #pragma unroll
            for (int j = 0; j < 9; ++j) acc = fmaf(de[j], e[r + j], acc);
            #pragma unroll
            for (int j = 0; j < 8; ++j) acc = fmaf(dd[j], o[r + j], acc);
            z[r] = acc;
        }
        float4* op = reinterpret_cast<float4*>(&orow[t0 + base]);
        op[0] = make_float4(z[0], z[1], z[2], z[3]);
        op[1] = make_float4(z[4], z[5], z[6], z[7]);
    }
}

extern "C" void kernel_launch(void* const* d_in, const int* in_sizes, int n_in,
                              void* d_out, int out_size, void* d_ws, size_t ws_size,
                              hipStream_t stream) {
    const float* x  = (const float*)d_in[0];
    const float* up = (const float*)d_in[1];
    const float* dn = (const float*)d_in[2];
    float* out      = (float*)d_out;

    const int rows = in_sizes[0] / T_LEN;        // 2048
    dim3 grid(rows * NTILES);                    // 32768 blocks
    flrelu_pad<<<grid, 256, 0, stream>>>(x, up, dn, out);
}

// Round 5
// 165.609 us; speedup vs baseline: 1.3211x; 1.2324x over previous
//
#include <hip/hip_runtime.h>

// FilteredLReLU: up2(17-tap) -> *2 -> lrelu(0.01) -> down2(17-tap), fused.
// LDS-free streaming, 16 outputs/thread fully in registers.
//   ge[m] = lrelu( sum_{j=0..8} fe[j]*x[m-4+j] )   if 0<=m<T else 0
//   go[m] = lrelu( sum_{j=0..7} fo[j]*x[m-3+j] )   if 0<=m<T else 0
//   z[t]  = sum_{j=0..8} de[j]*ge[t-4+j] + sum_{j=0..7} dd[j]*go[t-4+j]
// (UP gain of 2 folded into fe/fo.)  lrelu(v) == max(v, 0.01*v).

#define T_LEN 32768
#define R_OUT 16
#define TPR   (T_LEN / R_OUT)   // 2048 threads per row

__device__ __forceinline__ float lrelu(float v) {
    return fmaxf(v, 0.01f * v);   // 2 VALU ops, exact for all v
}

template <bool FAST>
__device__ __forceinline__ void compute16(
    const float* __restrict__ xrow, float* __restrict__ orow, int t,
    const float* fe, const float* fo, const float* de, const float* dd)
{
    float xv[R_OUT + 16];   // x[t-8 .. t+23]

    if (FAST) {
        const float4* xp = reinterpret_cast<const float4*>(xrow + t - 8);
        #pragma unroll
        for (int k = 0; k < (R_OUT + 16) / 4; ++k) {
            float4 v = xp[k];
            xv[4 * k + 0] = v.x; xv[4 * k + 1] = v.y;
            xv[4 * k + 2] = v.z; xv[4 * k + 3] = v.w;
        }
    } else {
        #pragma unroll
        for (int i = 0; i < R_OUT + 16; ++i) {
            int g = t - 8 + i;
            xv[i] = (g >= 0 && g < T_LEN) ? xrow[g] : 0.0f;
        }
    }

    float acc[R_OUT];
    #pragma unroll
    for (int r = 0; r < R_OUT; ++r) acc[r] = 0.0f;

    // even phase: ge[m], m = t-4+ml, scatter into acc as soon as computed
    #pragma unroll
    for (int ml = 0; ml < R_OUT + 8; ++ml) {
        float ae = 0.0f;
        #pragma unroll
        for (int j = 0; j < 9; ++j) ae = fmaf(fe[j], xv[ml + j], ae);
        float g = lrelu(ae);
        if (!FAST) {
            int m = t - 4 + ml;
            if (m < 0 || m >= T_LEN) g = 0.0f;   // dn conv zero-pads y
        }
        #pragma unroll
        for (int r = 0; r < R_OUT; ++r)
            if (r >= ml - 8 && r <= ml)
                acc[r] = fmaf(de[ml - r], g, acc[r]);
    }

    // odd phase: go[m]
    #pragma unroll
    for (int ml = 0; ml < R_OUT + 7; ++ml) {
        float ao = 0.0f;
        #pragma unroll
        for (int j = 0; j < 8; ++j) ao = fmaf(fo[j], xv[ml + 1 + j], ao);
        float g = lrelu(ao);
        if (!FAST) {
            int m = t - 4 + ml;
            if (m < 0 || m >= T_LEN) g = 0.0f;
        }
        #pragma unroll
        for (int r = 0; r < R_OUT; ++r)
            if (r >= ml - 7 && r <= ml)
                acc[r] = fmaf(dd[ml - r], g, acc[r]);
    }

    float4* op = reinterpret_cast<float4*>(orow + t);
    #pragma unroll
    for (int k = 0; k < R_OUT / 4; ++k)
        op[k] = make_float4(acc[4 * k + 0], acc[4 * k + 1],
                            acc[4 * k + 2], acc[4 * k + 3]);
}

__global__ __launch_bounds__(256, 6) void flrelu_stream16(
    const float* __restrict__ x,
    const float* __restrict__ up,
    const float* __restrict__ dn,
    float* __restrict__ out)
{
    const int gid = blockIdx.x * 256 + threadIdx.x;
    const int row = gid >> 11;                 // / TPR
    const int t   = (gid & (TPR - 1)) * R_OUT;
    const float* __restrict__ xrow = x + (size_t)row * T_LEN;
    float* __restrict__ orow       = out + (size_t)row * T_LEN;

    // Filters: uniform read-only loads -> SGPRs. UP gain folded in.
    float fe[9], fo[8], de[9], dd[8];
    #pragma unroll
    for (int j = 0; j < 9; ++j) { fe[j] = 2.0f * up[2 * j]; de[j] = dn[2 * j]; }
    #pragma unroll
    for (int j = 0; j < 8; ++j) { fo[j] = 2.0f * up[2 * j + 1]; dd[j] = dn[2 * j + 1]; }

    if (t >= 8 && t + R_OUT + 8 <= T_LEN) {
        compute16<true>(xrow, orow, t, fe, fo, de, dd);
    } else {
        compute16<false>(xrow, orow, t, fe, fo, de, dd);
    }
}

extern "C" void kernel_launch(void* const* d_in, const int* in_sizes, int n_in,
                              void* d_out, int out_size, void* d_ws, size_t ws_size,
                              hipStream_t stream) {
    const float* x  = (const float*)d_in[0];
    const float* up = (const float*)d_in[1];
    const float* dn = (const float*)d_in[2];
    float* out      = (float*)d_out;

    const int rows    = in_sizes[0] / T_LEN;         // 2048
    const int threads = rows * TPR;                  // 4.19M
    flrelu_stream16<<<threads / 256, 256, 0, stream>>>(x, up, dn, out);
}

// Round 6
// 148.555 us; speedup vs baseline: 1.4727x; 1.1148x over previous
//
#include <hip/hip_runtime.h>

// FilteredLReLU: up2(17-tap) -> *2 -> lrelu(0.01) -> down2(17-tap), fused.
// LDS-free streaming, 16 outputs/thread fully in registers.
// Even/odd intermediates computed together per window position and
// scattered immediately -> short live ranges, no spills.
//
//   ge[m] = lrelu( sum_{j=0..8} fe[j]*x[m-4+j] )   if 0<=m<T else 0
//   go[m] = lrelu( sum_{j=0..7} fo[j]*x[m-3+j] )   if 0<=m<T else 0
//   z[t]  = sum_{j=0..8} de[j]*ge[t-4+j] + sum_{j=0..7} dd[j]*go[t-4+j]
// (UP gain of 2 folded into fe/fo.)  lrelu(v) == max(v, 0.01*v).

#define T_LEN 32768
#define R_OUT 16
#define TPR   (T_LEN / R_OUT)   // 2048 threads per row

__device__ __forceinline__ float lrelu(float v) {
    return fmaxf(v, 0.01f * v);   // exact: max(v, 0.01v) == leaky_relu
}

template <bool FAST>
__device__ __forceinline__ void compute16(
    const float* __restrict__ xrow, float* __restrict__ orow, int t,
    const float* fe, const float* fo, const float* de, const float* dd)
{
    float xv[R_OUT + 16];   // x[t-8 .. t+23]

    if (FAST) {
        const float4* xp = reinterpret_cast<const float4*>(xrow + t - 8);
        #pragma unroll
        for (int k = 0; k < (R_OUT + 16) / 4; ++k) {
            float4 v = xp[k];
            xv[4 * k + 0] = v.x; xv[4 * k + 1] = v.y;
            xv[4 * k + 2] = v.z; xv[4 * k + 3] = v.w;
        }
    } else {
        #pragma unroll
        for (int i = 0; i < R_OUT + 16; ++i) {
            int g = t - 8 + i;
            xv[i] = (g >= 0 && g < T_LEN) ? xrow[g] : 0.0f;
        }
    }

    float acc[R_OUT];
    #pragma unroll
    for (int r = 0; r < R_OUT; ++r) acc[r] = 0.0f;

    // One pass: at window position ml, compute ge[ml] (taps xv[ml..ml+8])
    // and go[ml] (taps xv[ml+1..ml+8]) together, scatter both into acc.
    // xv[ml] is dead after this iteration -> minimal live range.
    #pragma unroll
    for (int ml = 0; ml < R_OUT + 8; ++ml) {
        float ae = 0.0f;
        #pragma unroll
        for (int j = 0; j < 9; ++j) ae = fmaf(fe[j], xv[ml + j], ae);
        float g = lrelu(ae);
        if (!FAST) {
            int m = t - 4 + ml;
            if (m < 0 || m >= T_LEN) g = 0.0f;   // dn conv zero-pads y
        }
        #pragma unroll
        for (int r = 0; r < R_OUT; ++r)
            if (r >= ml - 8 && r <= ml)
                acc[r] = fmaf(de[ml - r], g, acc[r]);

        if (ml < R_OUT + 7) {
            float ao = 0.0f;
            #pragma unroll
            for (int j = 0; j < 8; ++j) ao = fmaf(fo[j], xv[ml + 1 + j], ao);
            float h = lrelu(ao);
            if (!FAST) {
                int m = t - 4 + ml;
                if (m < 0 || m >= T_LEN) h = 0.0f;
            }
            #pragma unroll
            for (int r = 0; r < R_OUT; ++r)
                if (r >= ml - 7 && r <= ml)
                    acc[r] = fmaf(dd[ml - r], h, acc[r]);
        }
    }

    float4* op = reinterpret_cast<float4*>(orow + t);
    #pragma unroll
    for (int k = 0; k < R_OUT / 4; ++k)
        op[k] = make_float4(acc[4 * k + 0], acc[4 * k + 1],
                            acc[4 * k + 2], acc[4 * k + 3]);
}

__global__ __launch_bounds__(256, 4) void flrelu_stream16b(
    const float* __restrict__ x,
    const float* __restrict__ up,
    const float* __restrict__ dn,
    float* __restrict__ out)
{
    const int gid = blockIdx.x * 256 + threadIdx.x;
    const int row = gid >> 11;                 // / TPR
    const int t   = (gid & (TPR - 1)) * R_OUT;
    const float* __restrict__ xrow = x + (size_t)row * T_LEN;
    float* __restrict__ orow       = out + (size_t)row * T_LEN;

    // Filters: uniform read-only loads -> SGPRs. UP gain folded in.
    float fe[9], fo[8], de[9], dd[8];
    #pragma unroll
    for (int j = 0; j < 9; ++j) { fe[j] = 2.0f * up[2 * j]; de[j] = dn[2 * j]; }
    #pragma unroll
    for (int j = 0; j < 8; ++j) { fo[j] = 2.0f * up[2 * j + 1]; dd[j] = dn[2 * j + 1]; }

    if (t >= 8 && t + R_OUT + 8 <= T_LEN) {
        compute16<true>(xrow, orow, t, fe, fo, de, dd);
    } else {
        compute16<false>(xrow, orow, t, fe, fo, de, dd);
    }
}

extern "C" void kernel_launch(void* const* d_in, const int* in_sizes, int n_in,
                              void* d_out, int out_size, void* d_ws, size_t ws_size,
                              hipStream_t stream) {
    const float* x  = (const float*)d_in[0];
    const float* up = (const float*)d_in[1];
    const float* dn = (const float*)d_in[2];
    float* out      = (float*)d_out;

    const int rows    = in_sizes[0] / T_LEN;         // 2048
    const int threads = rows * TPR;                  // 4.19M
    flrelu_stream16b<<<threads / 256, 256, 0, stream>>>(x, up, dn, out);
}